// Round 1
// baseline (424.258 us; speedup 1.0000x reference)
//
#include <hip/hip_runtime.h>

#define SEQ 64
#define NXI 4
#define NSF 5

__device__ __forceinline__ float fsig(float x) {
    return 1.0f / (1.0f + __expf(-x));
}
__device__ __forceinline__ float ftanh(float x) {
    return 1.0f - 2.0f / (__expf(2.0f * x) + 1.0f);
}

// One batch element per wave. lane = (j, kh): j owns hidden unit, kh owns a
// 16-wide half of the k-reduction (weights in registers). LDS holds the
// layer-1 output history per wave (pitch 36 words -> 16B aligned, no bank
// conflicts on the hot paths).
__global__ __launch_bounds__(256) void lstm2_kernel(
    const float* __restrict__ xin,   // [B,64,4]
    const float* __restrict__ sfc,   // [B,5]
    const float* __restrict__ w_sfc1, const float* __restrict__ b_sfc1,
    const float* __restrict__ w_sfc2, const float* __restrict__ b_sfc2,
    const float* __restrict__ w_ih1, const float* __restrict__ w_hh1,
    const float* __restrict__ b_ih1, const float* __restrict__ b_hh1,
    const float* __restrict__ w_ih2, const float* __restrict__ w_hh2,
    const float* __restrict__ b_ih2, const float* __restrict__ b_hh2,
    const float* __restrict__ w_out, const float* __restrict__ b_out,
    float* __restrict__ out)         // [B,64,1]
{
    __shared__ float hist[4][65][36];
    const int wave = threadIdx.x >> 6;
    const int lane = threadIdx.x & 63;
    const int j    = lane & 31;
    const int kh   = lane >> 5;
    const int b    = (blockIdx.x << 2) + wave;
    float* hw = &hist[wave][0][0];

    // ---- surface MLP -> h0, c0 of layer 1 ----
    float a1 = b_sfc1[j], a2 = b_sfc2[j];
#pragma unroll
    for (int i = 0; i < NSF; ++i) {
        float s = sfc[b * NSF + i];
        a1 = fmaf(s, w_sfc1[j * NSF + i], a1);
        a2 = fmaf(s, w_sfc2[j * NSF + i], a2);
    }
    float c1 = ftanh(a2);
    if (kh == 0) hw[64 * 36 + j] = ftanh(a1);   // h0 in slot 64

    // ---- layer-1 weights (per-thread k-half) ----
    float whh1r[4][16], wih1r[4][NXI], bias1[4];
#pragma unroll
    for (int g = 0; g < 4; ++g) {
        const int row = g * 32 + j;
        const float4* p = (const float4*)(w_hh1 + row * 32 + kh * 16);
        *(float4*)&whh1r[g][0]  = p[0];
        *(float4*)&whh1r[g][4]  = p[1];
        *(float4*)&whh1r[g][8]  = p[2];
        *(float4*)&whh1r[g][12] = p[3];
        const float4 wi = *(const float4*)(w_ih1 + row * NXI);
        wih1r[g][0] = wi.x; wih1r[g][1] = wi.y; wih1r[g][2] = wi.z; wih1r[g][3] = wi.w;
        bias1[g] = b_ih1[row] + b_hh1[row];
    }

    // ---- phase 1: layer-1 LSTM over reversed time ----
    // hist[t] <- h after absorbing x[t] (scan went 63..t), i.e. out1[t]
    float4 xt = *(const float4*)(xin + (b * SEQ + (SEQ - 1)) * NXI);
#pragma unroll 1
    for (int t = SEQ - 1; t >= 0; --t) {
        float4 xt_n = *(const float4*)(xin + (b * SEQ + (t > 0 ? t - 1 : 0)) * NXI);
        float hk[16];
        const float* hp = hw + (t + 1) * 36 + kh * 16;
        *(float4*)&hk[0]  = *(const float4*)(hp + 0);
        *(float4*)&hk[4]  = *(const float4*)(hp + 4);
        *(float4*)&hk[8]  = *(const float4*)(hp + 8);
        *(float4*)&hk[12] = *(const float4*)(hp + 12);
        float p0 = 0.f, p1 = 0.f, p2 = 0.f, p3 = 0.f;
#pragma unroll
        for (int kk = 0; kk < 16; ++kk) {
            p0 = fmaf(hk[kk], whh1r[0][kk], p0);
            p1 = fmaf(hk[kk], whh1r[1][kk], p1);
            p2 = fmaf(hk[kk], whh1r[2][kk], p2);
            p3 = fmaf(hk[kk], whh1r[3][kk], p3);
        }
        p0 += __shfl_xor(p0, 32, 64);
        p1 += __shfl_xor(p1, 32, 64);
        p2 += __shfl_xor(p2, 32, 64);
        p3 += __shfl_xor(p3, 32, 64);
        p0 += bias1[0] + xt.x*wih1r[0][0] + xt.y*wih1r[0][1] + xt.z*wih1r[0][2] + xt.w*wih1r[0][3];
        p1 += bias1[1] + xt.x*wih1r[1][0] + xt.y*wih1r[1][1] + xt.z*wih1r[1][2] + xt.w*wih1r[1][3];
        p2 += bias1[2] + xt.x*wih1r[2][0] + xt.y*wih1r[2][1] + xt.z*wih1r[2][2] + xt.w*wih1r[2][3];
        p3 += bias1[3] + xt.x*wih1r[3][0] + xt.y*wih1r[3][1] + xt.z*wih1r[3][2] + xt.w*wih1r[3][3];
        const float ig = fsig(p0), fg = fsig(p1), gg = ftanh(p2), og = fsig(p3);
        c1 = fmaf(fg, c1, ig * gg);
        const float h1 = og * ftanh(c1);
        if (kh == 0) hw[t * 36 + j] = h1;
        xt = xt_n;
    }

    // ---- layer-2 weights ----
    float whh2r[4][16], wih2r[4][16], bias2[4];
#pragma unroll
    for (int g = 0; g < 4; ++g) {
        const int row = g * 32 + j;
        const float4* ph = (const float4*)(w_hh2 + row * 32 + kh * 16);
        *(float4*)&whh2r[g][0]  = ph[0];
        *(float4*)&whh2r[g][4]  = ph[1];
        *(float4*)&whh2r[g][8]  = ph[2];
        *(float4*)&whh2r[g][12] = ph[3];
        const float4* pi = (const float4*)(w_ih2 + row * 32 + kh * 16);
        *(float4*)&wih2r[g][0]  = pi[0];
        *(float4*)&wih2r[g][4]  = pi[1];
        *(float4*)&wih2r[g][8]  = pi[2];
        *(float4*)&wih2r[g][12] = pi[3];
        bias2[g] = b_ih2[row] + b_hh2[row];
    }
    if (kh == 0) hw[64 * 36 + j] = 0.0f;   // h2_{-1} = 0 (reuse slot 64)
    float c2 = 0.0f;

    // ---- phase 2: layer-2 forward; hist[t] <- h2[t] (overwrite out1[t]) ----
#pragma unroll 1
    for (int t = 0; t < SEQ; ++t) {
        const int ps = (t == 0) ? 64 : (t - 1);
        float hk[16], xk[16];
        const float* hp = hw + ps * 36 + kh * 16;
        const float* xp = hw + t  * 36 + kh * 16;
        *(float4*)&hk[0]  = *(const float4*)(hp + 0);
        *(float4*)&hk[4]  = *(const float4*)(hp + 4);
        *(float4*)&hk[8]  = *(const float4*)(hp + 8);
        *(float4*)&hk[12] = *(const float4*)(hp + 12);
        *(float4*)&xk[0]  = *(const float4*)(xp + 0);
        *(float4*)&xk[4]  = *(const float4*)(xp + 4);
        *(float4*)&xk[8]  = *(const float4*)(xp + 8);
        *(float4*)&xk[12] = *(const float4*)(xp + 12);
        float p0 = 0.f, p1 = 0.f, p2 = 0.f, p3 = 0.f;
#pragma unroll
        for (int kk = 0; kk < 16; ++kk) {
            p0 = fmaf(hk[kk], whh2r[0][kk], p0);
            p1 = fmaf(hk[kk], whh2r[1][kk], p1);
            p2 = fmaf(hk[kk], whh2r[2][kk], p2);
            p3 = fmaf(hk[kk], whh2r[3][kk], p3);
            p0 = fmaf(xk[kk], wih2r[0][kk], p0);
            p1 = fmaf(xk[kk], wih2r[1][kk], p1);
            p2 = fmaf(xk[kk], wih2r[2][kk], p2);
            p3 = fmaf(xk[kk], wih2r[3][kk], p3);
        }
        p0 += __shfl_xor(p0, 32, 64);
        p1 += __shfl_xor(p1, 32, 64);
        p2 += __shfl_xor(p2, 32, 64);
        p3 += __shfl_xor(p3, 32, 64);
        p0 += bias2[0]; p1 += bias2[1]; p2 += bias2[2]; p3 += bias2[3];
        const float ig = fsig(p0), fg = fsig(p1), gg = ftanh(p2), og = fsig(p3);
        c2 = fmaf(fg, c2, ig * gg);
        const float h2v = og * ftanh(c2);
        if (kh == 0) hw[t * 36 + j] = h2v;
    }

    __syncthreads();  // cheap safety before the cross-lane final read pattern

    // ---- output projection: lane t computes y[b, t] ----
    const float* hrow = hw + lane * 36;
    float y = b_out[0];
#pragma unroll
    for (int jj = 0; jj < 32; ++jj)
        y = fmaf(hrow[jj], w_out[jj], y);
    out[b * SEQ + lane] = y;
}

extern "C" void kernel_launch(void* const* d_in, const int* in_sizes, int n_in,
                              void* d_out, int out_size, void* d_ws, size_t ws_size,
                              hipStream_t stream) {
    const float* xin    = (const float*)d_in[0];
    const float* sfc    = (const float*)d_in[1];
    const float* w_sfc1 = (const float*)d_in[2];
    const float* b_sfc1 = (const float*)d_in[3];
    const float* w_sfc2 = (const float*)d_in[4];
    const float* b_sfc2 = (const float*)d_in[5];
    const float* w_ih1  = (const float*)d_in[6];
    const float* w_hh1  = (const float*)d_in[7];
    const float* b_ih1  = (const float*)d_in[8];
    const float* b_hh1  = (const float*)d_in[9];
    const float* w_ih2  = (const float*)d_in[10];
    const float* w_hh2  = (const float*)d_in[11];
    const float* b_ih2  = (const float*)d_in[12];
    const float* b_hh2  = (const float*)d_in[13];
    const float* w_out  = (const float*)d_in[14];
    const float* b_out  = (const float*)d_in[15];
    float* out = (float*)d_out;

    dim3 grid(8192 / 4);
    dim3 block(256);
    hipLaunchKernelGGL(lstm2_kernel, grid, block, 0, stream,
                       xin, sfc, w_sfc1, b_sfc1, w_sfc2, b_sfc2,
                       w_ih1, w_hh1, b_ih1, b_hh1,
                       w_ih2, w_hh2, b_ih2, b_hh2,
                       w_out, b_out, out);
}

// Round 2
// 234.215 us; speedup vs baseline: 1.8114x; 1.8114x over previous
//
#include <hip/hip_runtime.h>

typedef __attribute__((ext_vector_type(4))) float f32x4;
typedef __attribute__((ext_vector_type(8))) short bf16x8;

#define LOG2E 1.44269504088896340736f

__device__ __forceinline__ float bcf(unsigned u){ union{unsigned u;float f;}v; v.u=u; return v.f; }

// v_cvt_pk_bf16_f32: dst.lo = bf16(a), dst.hi = bf16(b), RNE
__device__ __forceinline__ unsigned pkbf(float a, float b){
    unsigned w; asm("v_cvt_pk_bf16_f32 %0, %1, %2" : "=v"(w) : "v"(a), "v"(b)); return w;
}

union FragU { unsigned w[4]; bf16x8 v; };

// split 8 f32 into hi/lo bf16 fragments (pairs (v0,v1)->word0 etc.)
__device__ __forceinline__ void split8(const float* v, bf16x8 &fh, bf16x8 &fl){
    FragU H, L;
#pragma unroll
    for (int i=0;i<4;i++){
        unsigned w = pkbf(v[2*i], v[2*i+1]);
        H.w[i] = w;
        float ra = v[2*i]   - bcf(w<<16);
        float rb = v[2*i+1] - bcf(w & 0xffff0000u);
        L.w[i] = pkbf(ra, rb);
    }
    fh = H.v; fl = L.v;
}

__device__ __forceinline__ float ex2(float x){ return __builtin_amdgcn_exp2f(x); }
__device__ __forceinline__ float rcp_(float x){ return __builtin_amdgcn_rcpf(x); }

#define MFMA(a,b,c) __builtin_amdgcn_mfma_f32_16x16x32_bf16(a,b,c,0,0,0)

// write h-state (true fp32 values, pair order p: j = 4*hi + (p&3) + 16*(p>>2))
// into hTh/hTl as bf16 hi/lo, layout [b][j] with row pitch 20 words (40 bf16).
__device__ __forceinline__ void store_state(unsigned* hTh, unsigned* hTl,
                                            int b15, int hi, const float* hv){
    unsigned hw[4], lw[4];
#pragma unroll
    for (int i=0;i<4;i++){
        unsigned w = pkbf(hv[2*i], hv[2*i+1]);
        hw[i] = w;
        float ra = hv[2*i]   - bcf(w<<16);
        float rb = hv[2*i+1] - bcf(w & 0xffff0000u);
        lw[i] = pkbf(ra, rb);
    }
    const int base = b15*20;
    hTh[base + 2*hi]     = hw[0];
    hTh[base + 2*hi + 1] = hw[1];
    hTh[base + 8 + 2*hi]     = hw[2];
    hTh[base + 8 + 2*hi + 1] = hw[3];
    hTl[base + 2*hi]     = lw[0];
    hTl[base + 2*hi + 1] = lw[1];
    hTl[base + 8 + 2*hi]     = lw[2];
    hTl[base + 8 + 2*hi + 1] = lw[3];
}

__global__ __launch_bounds__(64) void lstm2_mfma(
    const float* __restrict__ xin,   // [8192,64,4]
    const float* __restrict__ sfc,   // [8192,5]
    const float* __restrict__ w_sfc1, const float* __restrict__ b_sfc1,
    const float* __restrict__ w_sfc2, const float* __restrict__ b_sfc2,
    const float* __restrict__ w_ih1, const float* __restrict__ w_hh1,
    const float* __restrict__ b_ih1, const float* __restrict__ b_hh1,
    const float* __restrict__ w_ih2, const float* __restrict__ w_hh2,
    const float* __restrict__ b_ih2, const float* __restrict__ b_hh2,
    const float* __restrict__ w_out, const float* __restrict__ b_out,
    float* __restrict__ outp)        // [8192,64,1]
{
    // layer-1 output history, i16 q15, layout [t][b][16 words (32 i16)]
    __shared__ __align__(16) unsigned out1q[64*16*16];   // 64 KiB
    __shared__ __align__(16) unsigned hTh[16*20];        // h-state hi bf16, [b][j] pitch 40
    __shared__ __align__(16) unsigned hTl[16*20];        // h-state lo bf16
    __shared__ float ybuf[64][16];

    const int lane = threadIdx.x;       // single wave per block
    const int b15  = lane & 15;         // batch (B-frag col / D col); g-row for A-frags
    const int hi   = lane >> 4;         // k-block (A/B frag) / row-quad (D)
    const int B0   = blockIdx.x * 16;

    // ---------------- layer-1 weight fragments (A-layout: row=lane&15, k=8*hi+e) ----
    bf16x8 Whh_h[8], Whh_l[8], Wx_h[8], Wx_l[8];
#pragma unroll
    for (int T=0; T<8; ++T){
        const int g = 16*T + b15;
        const float sc = (T==4 || T==5) ? (2.0f*LOG2E) : (-LOG2E);  // g-gate vs i/f/o
        float wv[8];
        {
            float4 wa = *(const float4*)(w_hh1 + g*32 + 8*hi);
            float4 wb = *(const float4*)(w_hh1 + g*32 + 8*hi + 4);
            wv[0]=wa.x*sc; wv[1]=wa.y*sc; wv[2]=wa.z*sc; wv[3]=wa.w*sc;
            wv[4]=wb.x*sc; wv[5]=wb.y*sc; wv[6]=wb.z*sc; wv[7]=wb.w*sc;
        }
        split8(wv, Whh_h[T], Whh_l[T]);
        float xv[8] = {0,0,0,0,0,0,0,0};
        if (hi == 0){
            float4 wi = *(const float4*)(w_ih1 + g*4);
            xv[0]=wi.x*sc; xv[1]=wi.y*sc; xv[2]=wi.z*sc; xv[3]=wi.w*sc;
            xv[4]=(b_ih1[g] + b_hh1[g])*sc;   // bias rides k=4 against B2 k=4 == 1.0
        }
        split8(xv, Wx_h[T], Wx_l[T]);
    }

    // ---------------- surface MLP -> h0 (state), cs = 2log2e * c0 -------------------
    float cs[8], hv[8];
    {
        const float* sp = sfc + (B0 + b15)*5;
        const float s0=sp[0], s1=sp[1], s2=sp[2], s3=sp[3], s4=sp[4];
#pragma unroll
        for (int p=0;p<8;p++){
            const int j = 4*hi + (p&3) + 16*(p>>2);
            float a1 = b_sfc1[j] + s0*w_sfc1[j*5+0] + s1*w_sfc1[j*5+1]
                     + s2*w_sfc1[j*5+2] + s3*w_sfc1[j*5+3] + s4*w_sfc1[j*5+4];
            float a2 = b_sfc2[j] + s0*w_sfc2[j*5+0] + s1*w_sfc2[j*5+1]
                     + s2*w_sfc2[j*5+2] + s3*w_sfc2[j*5+3] + s4*w_sfc2[j*5+4];
            hv[p] = 1.0f - 2.0f*rcp_(ex2((2.0f*LOG2E)*a1)+1.0f);       // tanh(a1)
            cs[p] = (2.0f*LOG2E)*(1.0f - 2.0f*rcp_(ex2((2.0f*LOG2E)*a2)+1.0f));
        }
    }
    store_state(hTh, hTl, b15, hi, hv);

    // ---------------- phase 1: layer-1 LSTM over reversed time ----------------------
    float4 xt = *(const float4*)(xin + ((B0 + b15)*64 + 63)*4);
#pragma unroll 1
    for (int t=63; t>=0; --t){
        float4 xn = *(const float4*)(xin + ((B0 + b15)*64 + (t ? t-1 : 0))*4);

        // B2 frag: k0..3 = x_t, k4 = 1.0 (bias lane), only k-block hi==0 nonzero
        FragU BH, BL;
        {
            unsigned w0 = pkbf(xt.x, xt.y), w1 = pkbf(xt.z, xt.w);
            float l0 = xt.x - bcf(w0<<16), l1 = xt.y - bcf(w0 & 0xffff0000u);
            float l2 = xt.z - bcf(w1<<16), l3 = xt.w - bcf(w1 & 0xffff0000u);
            unsigned v0 = pkbf(l0,l1), v1 = pkbf(l2,l3);
            const bool z = (hi==0);
            BH.w[0] = z ? w0 : 0u; BH.w[1] = z ? w1 : 0u;
            BH.w[2] = z ? 0x00003f80u : 0u; BH.w[3] = 0u;
            BL.w[0] = z ? v0 : 0u; BL.w[1] = z ? v1 : 0u; BL.w[2]=0u; BL.w[3]=0u;
        }
        bf16x8 Hh = *(const bf16x8*)&hTh[b15*20 + 4*hi];
        bf16x8 Hl = *(const bf16x8*)&hTl[b15*20 + 4*hi];

        f32x4 acc[8];
#pragma unroll
        for (int T=0;T<8;T++){
            f32x4 a = {0.f,0.f,0.f,0.f};
            a = MFMA(Wx_h[T], BH.v, a);     // w_ih*x_hi + bias
            a = MFMA(Wx_h[T], BL.v, a);     // w_ih*x_lo
            a = MFMA(Wx_l[T], BH.v, a);     // w_ih_lo*x_hi + bias_lo
            a = MFMA(Whh_h[T], Hh, a);
            a = MFMA(Whh_h[T], Hl, a);
            a = MFMA(Whh_l[T], Hh, a);
            a = MFMA(Whh_l[T], Hl, a);
            acc[T] = a;
        }

        int q[8];
#pragma unroll
        for (int p=0;p<8;p++){
            float iv = acc[(p>>2)][p&3];
            float fv = acc[2+(p>>2)][p&3];
            float gv = acc[4+(p>>2)][p&3];
            float ov = acc[6+(p>>2)][p&3];
            float si = rcp_(1.0f+ex2(iv));
            float sf = rcp_(1.0f+ex2(fv));
            float so = rcp_(1.0f+ex2(ov));
            float tg = 1.0f - 2.0f*rcp_(ex2(gv)+1.0f);
            cs[p] = fmaf(sf, cs[p], ((2.0f*LOG2E)*si)*tg);
            float tc = 1.0f - 2.0f*rcp_(ex2(cs[p])+1.0f);
            hv[p] = so*tc;
            q[p] = __float2int_rn(hv[p]*32767.0f);
        }
        store_state(hTh, hTl, b15, hi, hv);
        // out1 history (i16): words indexed j/2; pairs (p0,p1)->2hi, (p2,p3)->2hi+1, ...
        {
            unsigned q01 = __builtin_amdgcn_perm((unsigned)q[1], (unsigned)q[0], 0x05040100u);
            unsigned q23 = __builtin_amdgcn_perm((unsigned)q[3], (unsigned)q[2], 0x05040100u);
            unsigned q45 = __builtin_amdgcn_perm((unsigned)q[5], (unsigned)q[4], 0x05040100u);
            unsigned q67 = __builtin_amdgcn_perm((unsigned)q[7], (unsigned)q[6], 0x05040100u);
            const int ob = (t*16 + b15)*16;
            out1q[ob + 2*hi]     = q01;
            out1q[ob + 2*hi + 1] = q23;
            out1q[ob + 8 + 2*hi]     = q45;
            out1q[ob + 8 + 2*hi + 1] = q67;
        }
        xt = xn;
    }

    // ---------------- layer-2 weights + bias ----------------------------------------
    bf16x8 W2h_h[8], W2h_l[8], W2x_h[8], W2x_l[8];
#pragma unroll
    for (int T=0;T<8;T++){
        const int g = 16*T + b15;
        const float sc  = (T==4||T==5) ? (2.0f*LOG2E) : (-LOG2E);
        const float scx = sc * (1.0f/32767.0f);        // fold q15 descale into w_ih2
        float wv[8];
        {
            float4 wa = *(const float4*)(w_hh2 + g*32 + 8*hi);
            float4 wb = *(const float4*)(w_hh2 + g*32 + 8*hi + 4);
            wv[0]=wa.x*sc; wv[1]=wa.y*sc; wv[2]=wa.z*sc; wv[3]=wa.w*sc;
            wv[4]=wb.x*sc; wv[5]=wb.y*sc; wv[6]=wb.z*sc; wv[7]=wb.w*sc;
        }
        split8(wv, W2h_h[T], W2h_l[T]);
        {
            float4 wa = *(const float4*)(w_ih2 + g*32 + 8*hi);
            float4 wb = *(const float4*)(w_ih2 + g*32 + 8*hi + 4);
            wv[0]=wa.x*scx; wv[1]=wa.y*scx; wv[2]=wa.z*scx; wv[3]=wa.w*scx;
            wv[4]=wb.x*scx; wv[5]=wb.y*scx; wv[6]=wb.z*scx; wv[7]=wb.w*scx;
        }
        split8(wv, W2x_h[T], W2x_l[T]);
    }
    float bia[4][8], woutr[8];
#pragma unroll
    for (int p=0;p<8;p++){
        const int j = 4*hi + (p&3) + 16*(p>>2);
        bia[0][p] = (b_ih2[j]      + b_hh2[j])      * (-LOG2E);
        bia[1][p] = (b_ih2[32+j]   + b_hh2[32+j])   * (-LOG2E);
        bia[2][p] = (b_ih2[64+j]   + b_hh2[64+j])   * (2.0f*LOG2E);
        bia[3][p] = (b_ih2[96+j]   + b_hh2[96+j])   * (-LOG2E);
        woutr[p]  = w_out[j];
        cs[p] = 0.0f;
    }
    {   // h2_{-1} = 0
        const int base = b15*20;
        hTh[base+2*hi]=0u; hTh[base+2*hi+1]=0u; hTh[base+8+2*hi]=0u; hTh[base+8+2*hi+1]=0u;
        hTl[base+2*hi]=0u; hTl[base+2*hi+1]=0u; hTl[base+8+2*hi]=0u; hTl[base+8+2*hi+1]=0u;
    }
    const float bout0 = b_out[0];

    // ---------------- phase 2: layer-2 forward + fused output projection ------------
#pragma unroll 1
    for (int t=0;t<64;t++){
        const int ob = (t*16 + b15)*16 + 4*hi;
        const uint4 w = *(const uint4*)&out1q[ob];
        float xv[8];
        xv[0]=(float)(short)(w.x & 0xffffu); xv[1]=(float)((int)w.x >> 16);
        xv[2]=(float)(short)(w.y & 0xffffu); xv[3]=(float)((int)w.y >> 16);
        xv[4]=(float)(short)(w.z & 0xffffu); xv[5]=(float)((int)w.z >> 16);
        xv[6]=(float)(short)(w.w & 0xffffu); xv[7]=(float)((int)w.w >> 16);
        bf16x8 Xh, Xl; split8(xv, Xh, Xl);   // exact: i16 == hi+lo bf16
        bf16x8 Hh = *(const bf16x8*)&hTh[b15*20 + 4*hi];
        bf16x8 Hl = *(const bf16x8*)&hTl[b15*20 + 4*hi];

        f32x4 acc[8];
#pragma unroll
        for (int T=0;T<8;T++){
            f32x4 a = {0.f,0.f,0.f,0.f};
            a = MFMA(W2x_h[T], Xh, a);
            a = MFMA(W2x_h[T], Xl, a);
            a = MFMA(W2x_l[T], Xh, a);
            a = MFMA(W2x_l[T], Xl, a);
            a = MFMA(W2h_h[T], Hh, a);
            a = MFMA(W2h_h[T], Hl, a);
            a = MFMA(W2h_l[T], Hh, a);
            a = MFMA(W2h_l[T], Hl, a);
            acc[T] = a;
        }

        float y = 0.0f;
#pragma unroll
        for (int p=0;p<8;p++){
            float iv = acc[(p>>2)][p&3]   + bia[0][p];
            float fv = acc[2+(p>>2)][p&3] + bia[1][p];
            float gv = acc[4+(p>>2)][p&3] + bia[2][p];
            float ov = acc[6+(p>>2)][p&3] + bia[3][p];
            float si = rcp_(1.0f+ex2(iv));
            float sf = rcp_(1.0f+ex2(fv));
            float so = rcp_(1.0f+ex2(ov));
            float tg = 1.0f - 2.0f*rcp_(ex2(gv)+1.0f);
            cs[p] = fmaf(sf, cs[p], ((2.0f*LOG2E)*si)*tg);
            float tc = 1.0f - 2.0f*rcp_(ex2(cs[p])+1.0f);
            hv[p] = so*tc;
            y = fmaf(hv[p], woutr[p], y);
        }
        store_state(hTh, hTl, b15, hi, hv);
        y += __shfl_xor(y, 16, 64);
        y += __shfl_xor(y, 32, 64);
        if (hi == 0) ybuf[t][b15] = y + bout0;
    }

    // ---------------- store y: [16b][64t] contiguous, fully coalesced ---------------
#pragma unroll
    for (int i=0;i<4;i++){
        const int bb = lane >> 2;
        const int t0 = (lane & 3)*16 + 4*i;
        float4 v;
        v.x = ybuf[t0+0][bb]; v.y = ybuf[t0+1][bb];
        v.z = ybuf[t0+2][bb]; v.w = ybuf[t0+3][bb];
        *(float4*)(outp + (B0 + bb)*64 + t0) = v;
    }
}

extern "C" void kernel_launch(void* const* d_in, const int* in_sizes, int n_in,
                              void* d_out, int out_size, void* d_ws, size_t ws_size,
                              hipStream_t stream) {
    const float* xin    = (const float*)d_in[0];
    const float* sfc    = (const float*)d_in[1];
    const float* w_sfc1 = (const float*)d_in[2];
    const float* b_sfc1 = (const float*)d_in[3];
    const float* w_sfc2 = (const float*)d_in[4];
    const float* b_sfc2 = (const float*)d_in[5];
    const float* w_ih1  = (const float*)d_in[6];
    const float* w_hh1  = (const float*)d_in[7];
    const float* b_ih1  = (const float*)d_in[8];
    const float* b_hh1  = (const float*)d_in[9];
    const float* w_ih2  = (const float*)d_in[10];
    const float* w_hh2  = (const float*)d_in[11];
    const float* b_ih2  = (const float*)d_in[12];
    const float* b_hh2  = (const float*)d_in[13];
    const float* w_out  = (const float*)d_in[14];
    const float* b_out  = (const float*)d_in[15];
    float* out = (float*)d_out;

    dim3 grid(8192 / 16);
    dim3 block(64);
    hipLaunchKernelGGL(lstm2_mfma, grid, block, 0, stream,
                       xin, sfc, w_sfc1, b_sfc1, w_sfc2, b_sfc2,
                       w_ih1, w_hh1, b_ih1, b_hh1,
                       w_ih2, w_hh2, b_ih2, b_hh2,
                       w_out, b_out, out);
}

// Round 3
// 175.144 us; speedup vs baseline: 2.4223x; 1.3373x over previous
//
#include <hip/hip_runtime.h>

typedef __attribute__((ext_vector_type(4))) float f32x4;
typedef __attribute__((ext_vector_type(8))) short bf16x8;

#define LOG2E 1.44269504088896340736f

__device__ __forceinline__ float bcf(unsigned u){ union{unsigned u;float f;}v; v.u=u; return v.f; }
__device__ __forceinline__ unsigned pkbf(float a, float b){
    unsigned w; asm("v_cvt_pk_bf16_f32 %0, %1, %2" : "=v"(w) : "v"(a), "v"(b)); return w;
}
__device__ __forceinline__ float ex2(float x){ return __builtin_amdgcn_exp2f(x); }
__device__ __forceinline__ float rcp_(float x){ return __builtin_amdgcn_rcpf(x); }

#define MFMA(a,b,c) __builtin_amdgcn_mfma_f32_16x16x32_bf16(a,b,c,0,0,0)

union FragU { unsigned w[4]; bf16x8 v; };

// split 8 f32 into hi/lo bf16 fragments
__device__ __forceinline__ void split8(const float* v, bf16x8 &fh, bf16x8 &fl){
    FragU H, L;
#pragma unroll
    for (int i=0;i<4;i++){
        unsigned w = pkbf(v[2*i], v[2*i+1]);
        H.w[i] = w;
        float ra = v[2*i]   - bcf(w<<16);
        float rb = v[2*i+1] - bcf(w & 0xffff0000u);
        L.w[i] = pkbf(ra, rb);
    }
    fh = H.v; fl = L.v;
}

// B-frag for packed x-MFMA: k = [xh(0-3), xl(4-7) | xh(8-11), 1@12, 1@13 | 0 | 0]
__device__ __forceinline__ void build_bx(const float4& x, int hi, FragU& B){
    unsigned w0 = pkbf(x.x, x.y), w1 = pkbf(x.z, x.w);
    float r0 = x.x - bcf(w0<<16), r1 = x.y - bcf(w0 & 0xffff0000u);
    float r2 = x.z - bcf(w1<<16), r3 = x.w - bcf(w1 & 0xffff0000u);
    unsigned l0 = pkbf(r0,r1), l1 = pkbf(r2,r3);
    const bool h01 = (hi < 2);
    B.w[0] = h01 ? w0 : 0u;
    B.w[1] = h01 ? w1 : 0u;
    B.w[2] = (hi==0) ? l0 : (hi==1 ? 0x3f803f80u : 0u);
    B.w[3] = (hi==0) ? l1 : 0u;
}

// write this lane's 4 h-values (j = 16w+4hi+p) as bf16 hi/lo into buffer
__device__ __forceinline__ void write_h(unsigned (*hb)[16][20], int b15, int hi, int wv_,
                                        const float* hv){
    unsigned h0 = pkbf(hv[0], hv[1]);
    unsigned h1 = pkbf(hv[2], hv[3]);
    float r0 = hv[0]-bcf(h0<<16), r1 = hv[1]-bcf(h0 & 0xffff0000u);
    float r2 = hv[2]-bcf(h1<<16), r3 = hv[3]-bcf(h1 & 0xffff0000u);
    unsigned l0 = pkbf(r0,r1), l1 = pkbf(r2,r3);
    const int wi = 8*wv_ + 2*hi;
    *(uint2*)&hb[0][b15][wi] = make_uint2(h0,h1);
    *(uint2*)&hb[1][b15][wi] = make_uint2(l0,l1);
}

__global__ __launch_bounds__(128) void lstm2_mfma2(
    const float* __restrict__ xin,   // [8192,64,4]
    const float* __restrict__ sfc,   // [8192,5]
    const float* __restrict__ w_sfc1, const float* __restrict__ b_sfc1,
    const float* __restrict__ w_sfc2, const float* __restrict__ b_sfc2,
    const float* __restrict__ w_ih1, const float* __restrict__ w_hh1,
    const float* __restrict__ b_ih1, const float* __restrict__ b_hh1,
    const float* __restrict__ w_ih2, const float* __restrict__ w_hh2,
    const float* __restrict__ b_ih2, const float* __restrict__ b_hh2,
    const float* __restrict__ w_out, const float* __restrict__ b_out,
    float* __restrict__ outp)        // [8192,64,1]
{
    __shared__ __align__(16) unsigned out1q[64][16][16];     // 64 KiB, i16 q15
    __shared__ __align__(16) unsigned hbuf[2][2][16][20];    // [par][hi/lo][b][words]
    __shared__ float ybuf[2][64][16];

    const int tid  = threadIdx.x;
    const int wv   = tid >> 6;          // wave 0/1 -> j-half
    const int lane = tid & 63;
    const int b15  = lane & 15;
    const int hi   = (lane >> 4) & 3;
    const int B0   = blockIdx.x * 16;

    // ================= weights (all upfront; 1 wave/SIMD so VGPRs are cheap) ======
    bf16x8 Whh_h[4], Whh_l[4], WxA[4];
    bf16x8 W2h_h[4], W2h_l[4], W2x_h[4], W2x_l[4];
    float bia[4][4], woutr[4];
#pragma unroll
    for (int c=0;c<4;c++){
        const int gr = 32*c + 16*wv + b15;
        const float sc = (c==2) ? (2.0f*LOG2E) : (-LOG2E);
        float wvv[8];
        {   // layer-1 hh
            float4 wa = *(const float4*)(w_hh1 + gr*32 + 8*hi);
            float4 wb = *(const float4*)(w_hh1 + gr*32 + 8*hi + 4);
            wvv[0]=wa.x*sc; wvv[1]=wa.y*sc; wvv[2]=wa.z*sc; wvv[3]=wa.w*sc;
            wvv[4]=wb.x*sc; wvv[5]=wb.y*sc; wvv[6]=wb.z*sc; wvv[7]=wb.w*sc;
        }
        split8(wvv, Whh_h[c], Whh_l[c]);
        {   // layer-1 ih, packed A: hi0=[wh|wh], hi1=[wl|bias_hi,bias_lo,0,0]
            float4 wi = *(const float4*)(w_ih1 + gr*4);
            float wh0=wi.x*sc, wh1=wi.y*sc, wh2=wi.z*sc, wh3=wi.w*sc;
            unsigned xw0 = pkbf(wh0,wh1), xw1 = pkbf(wh2,wh3);
            float wl0 = wh0-bcf(xw0<<16), wl1 = wh1-bcf(xw0 & 0xffff0000u);
            float wl2 = wh2-bcf(xw1<<16), wl3 = wh3-bcf(xw1 & 0xffff0000u);
            unsigned lw0 = pkbf(wl0,wl1), lw1 = pkbf(wl2,wl3);
            float bias = (b_ih1[gr] + b_hh1[gr])*sc;
            unsigned bh = pkbf(bias, 0.0f);
            float blo = bias - bcf(bh<<16);
            unsigned bword = pkbf(bias, blo);
            FragU A;
            if (hi==0){ A.w[0]=xw0; A.w[1]=xw1; A.w[2]=xw0; A.w[3]=xw1; }
            else if (hi==1){ A.w[0]=lw0; A.w[1]=lw1; A.w[2]=bword; A.w[3]=0u; }
            else { A.w[0]=0u; A.w[1]=0u; A.w[2]=0u; A.w[3]=0u; }
            WxA[c] = A.v;
        }
        {   // layer-2 hh
            float4 wa = *(const float4*)(w_hh2 + gr*32 + 8*hi);
            float4 wb = *(const float4*)(w_hh2 + gr*32 + 8*hi + 4);
            wvv[0]=wa.x*sc; wvv[1]=wa.y*sc; wvv[2]=wa.z*sc; wvv[3]=wa.w*sc;
            wvv[4]=wb.x*sc; wvv[5]=wb.y*sc; wvv[6]=wb.z*sc; wvv[7]=wb.w*sc;
        }
        split8(wvv, W2h_h[c], W2h_l[c]);
        {   // layer-2 ih (q15 descale folded)
            const float scx = sc * (1.0f/32767.0f);
            float4 wa = *(const float4*)(w_ih2 + gr*32 + 8*hi);
            float4 wb = *(const float4*)(w_ih2 + gr*32 + 8*hi + 4);
            wvv[0]=wa.x*scx; wvv[1]=wa.y*scx; wvv[2]=wa.z*scx; wvv[3]=wa.w*scx;
            wvv[4]=wb.x*scx; wvv[5]=wb.y*scx; wvv[6]=wb.z*scx; wvv[7]=wb.w*scx;
        }
        split8(wvv, W2x_h[c], W2x_l[c]);
    }
#pragma unroll
    for (int p=0;p<4;p++){
        const int j = 16*wv + 4*hi + p;
        bia[0][p] = (b_ih2[j]    + b_hh2[j])    * (-LOG2E);
        bia[1][p] = (b_ih2[32+j] + b_hh2[32+j]) * (-LOG2E);
        bia[2][p] = (b_ih2[64+j] + b_hh2[64+j]) * (2.0f*LOG2E);
        bia[3][p] = (b_ih2[96+j] + b_hh2[96+j]) * (-LOG2E);
        woutr[p]  = w_out[j];
    }

    // ================= surface MLP -> h0, cs0 =====================================
    float cs[4], hv[4];
    {
        const float* sp = sfc + (B0 + b15)*5;
        const float s0=sp[0], s1=sp[1], s2=sp[2], s3=sp[3], s4=sp[4];
#pragma unroll
        for (int p=0;p<4;p++){
            const int j = 16*wv + 4*hi + p;
            float a1 = b_sfc1[j] + s0*w_sfc1[j*5+0] + s1*w_sfc1[j*5+1]
                     + s2*w_sfc1[j*5+2] + s3*w_sfc1[j*5+3] + s4*w_sfc1[j*5+4];
            float a2 = b_sfc2[j] + s0*w_sfc2[j*5+0] + s1*w_sfc2[j*5+1]
                     + s2*w_sfc2[j*5+2] + s3*w_sfc2[j*5+3] + s4*w_sfc2[j*5+4];
            hv[p] = 1.0f - 2.0f*rcp_(ex2((2.0f*LOG2E)*a1)+1.0f);
            cs[p] = (2.0f*LOG2E)*(1.0f - 2.0f*rcp_(ex2((2.0f*LOG2E)*a2)+1.0f));
        }
    }
    write_h(hbuf[0], b15, hi, wv, hv);
    __syncthreads();

    // ================= phase 1: layer-1 LSTM, reversed time =======================
    int par = 0;
    FragU Bx;
    {
        float4 x0 = *(const float4*)(xin + ((B0 + b15)*64 + 63)*4);
        build_bx(x0, hi, Bx);
    }
#pragma unroll 1
    for (int t=63; t>=0; --t){
        bf16x8 Hh = *(const bf16x8*)&hbuf[par][0][b15][4*hi];
        bf16x8 Hl = *(const bf16x8*)&hbuf[par][1][b15][4*hi];
        f32x4 acc[4];
#pragma unroll
        for (int c=0;c<4;c++){
            f32x4 a = {0.f,0.f,0.f,0.f};
            a = MFMA(WxA[c],   Bx.v, a);   // wh*xh + wh*xl + wl*xh + bias (packed k)
            a = MFMA(Whh_h[c], Hh,   a);
            a = MFMA(Whh_h[c], Hl,   a);
            a = MFMA(Whh_l[c], Hh,   a);
            acc[c] = a;
        }
        if (t){   // build next step's x operand while MFMAs complete
            float4 xn = *(const float4*)(xin + ((B0 + b15)*64 + (t-1))*4);
            build_bx(xn, hi, Bx);
        }
        int q[4];
#pragma unroll
        for (int p=0;p<4;p++){
            float iv = acc[0][p], fv = acc[1][p], gv = acc[2][p], ov = acc[3][p];
            float si = rcp_(1.0f+ex2(iv));
            float sf = rcp_(1.0f+ex2(fv));
            float so = rcp_(1.0f+ex2(ov));
            float tg = 1.0f - 2.0f*rcp_(ex2(gv)+1.0f);
            cs[p] = fmaf(sf, cs[p], ((2.0f*LOG2E)*si)*tg);
            float tc = 1.0f - 2.0f*rcp_(ex2(cs[p])+1.0f);
            hv[p] = so*tc;
            q[p] = __float2int_rn(hv[p]*32767.0f);
        }
        unsigned q01 = ((unsigned)q[0] & 0xffffu) | ((unsigned)q[1] << 16);
        unsigned q23 = ((unsigned)q[2] & 0xffffu) | ((unsigned)q[3] << 16);
        *(uint2*)&out1q[t][b15][8*wv + 2*hi] = make_uint2(q01, q23);
        write_h(hbuf[par^1], b15, hi, wv, hv);
        __syncthreads();
        par ^= 1;
    }

    // ================= phase 1 -> 2: zero state, prefetch X0 ======================
    {
        const int wi = 8*wv + 2*hi;
        *(uint2*)&hbuf[par][0][b15][wi] = make_uint2(0u,0u);
        *(uint2*)&hbuf[par][1][b15][wi] = make_uint2(0u,0u);
        cs[0]=0.f; cs[1]=0.f; cs[2]=0.f; cs[3]=0.f;
    }
    FragU Xh, Xl;
    {
        const uint4 xw = *(const uint4*)&out1q[0][b15][4*hi];
        float xv[8];
        xv[0]=(float)(short)(xw.x & 0xffffu); xv[1]=(float)((int)xw.x >> 16);
        xv[2]=(float)(short)(xw.y & 0xffffu); xv[3]=(float)((int)xw.y >> 16);
        xv[4]=(float)(short)(xw.z & 0xffffu); xv[5]=(float)((int)xw.z >> 16);
        xv[6]=(float)(short)(xw.w & 0xffffu); xv[7]=(float)((int)xw.w >> 16);
        split8(xv, Xh.v, Xl.v);
    }
    __syncthreads();

    // ================= phase 2: layer-2 LSTM + fused output =======================
#pragma unroll 1
    for (int t=0; t<64; ++t){
        bf16x8 Hh = *(const bf16x8*)&hbuf[par][0][b15][4*hi];
        bf16x8 Hl = *(const bf16x8*)&hbuf[par][1][b15][4*hi];
        f32x4 acc[4];
#pragma unroll
        for (int c=0;c<4;c++){
            f32x4 a = {0.f,0.f,0.f,0.f};
            a = MFMA(W2x_h[c], Xh.v, a);
            a = MFMA(W2x_h[c], Xl.v, a);
            a = MFMA(W2x_l[c], Xh.v, a);
            a = MFMA(W2h_h[c], Hh,   a);
            a = MFMA(W2h_h[c], Hl,   a);
            a = MFMA(W2h_l[c], Hh,   a);
            acc[c] = a;
        }
        const int tn = (t < 63) ? t+1 : 63;
        const uint4 xw = *(const uint4*)&out1q[tn][b15][4*hi];

        float y = 0.0f;
#pragma unroll
        for (int p=0;p<4;p++){
            float iv = acc[0][p] + bia[0][p];
            float fv = acc[1][p] + bia[1][p];
            float gv = acc[2][p] + bia[2][p];
            float ov = acc[3][p] + bia[3][p];
            float si = rcp_(1.0f+ex2(iv));
            float sf = rcp_(1.0f+ex2(fv));
            float so = rcp_(1.0f+ex2(ov));
            float tg = 1.0f - 2.0f*rcp_(ex2(gv)+1.0f);
            cs[p] = fmaf(sf, cs[p], ((2.0f*LOG2E)*si)*tg);
            float tc = 1.0f - 2.0f*rcp_(ex2(cs[p])+1.0f);
            hv[p] = so*tc;
            y = fmaf(hv[p], woutr[p], y);
        }
        y += __shfl_xor(y, 16, 64);
        y += __shfl_xor(y, 32, 64);
        if (hi == 0) ybuf[wv][t][b15] = y;
        write_h(hbuf[par^1], b15, hi, wv, hv);
        {   // convert prefetched X for next step
            float xv[8];
            xv[0]=(float)(short)(xw.x & 0xffffu); xv[1]=(float)((int)xw.x >> 16);
            xv[2]=(float)(short)(xw.y & 0xffffu); xv[3]=(float)((int)xw.y >> 16);
            xv[4]=(float)(short)(xw.z & 0xffffu); xv[5]=(float)((int)xw.z >> 16);
            xv[6]=(float)(short)(xw.w & 0xffffu); xv[7]=(float)((int)xw.w >> 16);
            split8(xv, Xh.v, Xl.v);
        }
        __syncthreads();
        par ^= 1;
    }

    // ================= epilogue: combine wave halves, coalesced store =============
    const float bo = b_out[0];
    const int bb = tid >> 3;            // 0..15
    const int t0 = (tid & 7) * 8;       // 0..56
#pragma unroll
    for (int hlf=0; hlf<2; ++hlf){
        float4 v;
        v.x = ybuf[0][t0+4*hlf+0][bb] + ybuf[1][t0+4*hlf+0][bb] + bo;
        v.y = ybuf[0][t0+4*hlf+1][bb] + ybuf[1][t0+4*hlf+1][bb] + bo;
        v.z = ybuf[0][t0+4*hlf+2][bb] + ybuf[1][t0+4*hlf+2][bb] + bo;
        v.w = ybuf[0][t0+4*hlf+3][bb] + ybuf[1][t0+4*hlf+3][bb] + bo;
        *(float4*)(outp + (B0 + bb)*64 + t0 + 4*hlf) = v;
    }
}

extern "C" void kernel_launch(void* const* d_in, const int* in_sizes, int n_in,
                              void* d_out, int out_size, void* d_ws, size_t ws_size,
                              hipStream_t stream) {
    const float* xin    = (const float*)d_in[0];
    const float* sfc    = (const float*)d_in[1];
    const float* w_sfc1 = (const float*)d_in[2];
    const float* b_sfc1 = (const float*)d_in[3];
    const float* w_sfc2 = (const float*)d_in[4];
    const float* b_sfc2 = (const float*)d_in[5];
    const float* w_ih1  = (const float*)d_in[6];
    const float* w_hh1  = (const float*)d_in[7];
    const float* b_ih1  = (const float*)d_in[8];
    const float* b_hh1  = (const float*)d_in[9];
    const float* w_ih2  = (const float*)d_in[10];
    const float* w_hh2  = (const float*)d_in[11];
    const float* b_ih2  = (const float*)d_in[12];
    const float* b_hh2  = (const float*)d_in[13];
    const float* w_out  = (const float*)d_in[14];
    const float* b_out  = (const float*)d_in[15];
    float* out = (float*)d_out;

    dim3 grid(8192 / 16);
    dim3 block(128);
    hipLaunchKernelGGL(lstm2_mfma2, grid, block, 0, stream,
                       xin, sfc, w_sfc1, b_sfc1, w_sfc2, b_sfc2,
                       w_ih1, w_hh1, b_ih1, b_hh1,
                       w_ih2, w_hh2, b_ih2, b_hh2,
                       w_out, b_out, out);
}